// Round 6
// baseline (823.198 us; speedup 1.0000x reference)
//
#include <hip/hip_runtime.h>

#define DD 1024

typedef short short8 __attribute__((ext_vector_type(8)));   // 8 bf16 in 4 VGPRs
typedef float f32x4 __attribute__((ext_vector_type(4)));

__device__ __forceinline__ unsigned short f2bf(float f) {
  unsigned int u = __float_as_uint(f);
  unsigned int r = (u + 0x7FFFu + ((u >> 16) & 1u)) >> 16;   // RNE
  return (unsigned short)r;
}
__device__ __forceinline__ float sigm(float x) { return 1.0f / (1.0f + __expf(-x)); }
__device__ __forceinline__ float tanh_fast(float x) {
  float e = __expf(-2.0f * fabsf(x));
  float t = (1.0f - e) / (1.0f + e);
  return copysignf(t, x);
}
__device__ __forceinline__ void gload_lds16(const void* g, void* l) {
  __builtin_amdgcn_global_load_lds((const __attribute__((address_space(1))) void*)g,
                                   (__attribute__((address_space(3))) void*)l, 16, 0, 0);
}

// ---- one-time weight prep: Wcat[4][1024][1024] bf16, bias[4][1024] f32 ----
__global__ __launch_bounds__(256) void prep_weights(
    const float* __restrict__ Wih, const float* __restrict__ Whh,
    const float* __restrict__ bih, const float* __restrict__ bhh,
    unsigned short* __restrict__ Wcat, float* __restrict__ bias) {
  int i = blockIdx.x * 256 + threadIdx.x;
  int g = i >> 18;
  int rem = i & 262143;
  int n = rem >> 8;
  int k4 = rem & 255;
  const float4* wih4 = reinterpret_cast<const float4*>(Wih);
  const float4* whh4 = reinterpret_cast<const float4*>(Whh);
  float4 v;
  if (g == 0) {
    size_t idx = (size_t)n * 256 + k4;
    float4 a = wih4[idx], b = whh4[idx];
    v = make_float4(a.x + b.x, a.y + b.y, a.z + b.z, a.w + b.w);
  } else if (g == 1) {
    size_t idx = (size_t)(DD + n) * 256 + k4;
    float4 a = wih4[idx], b = whh4[idx];
    v = make_float4(a.x + b.x, a.y + b.y, a.z + b.z, a.w + b.w);
  } else if (g == 2) {
    size_t idx = (size_t)(2 * DD + n) * 256 + k4;
    v = wih4[idx];
  } else {
    size_t idx = (size_t)(2 * DD + n) * 256 + k4;
    v = whh4[idx];
  }
  ushort4 o = make_ushort4(f2bf(v.x), f2bf(v.y), f2bf(v.z), f2bf(v.w));
  reinterpret_cast<ushort4*>(Wcat)[i] = o;

  if (i < 4 * DD) {
    int bg = i >> 10, bn = i & 1023;
    float bv;
    if (bg == 0)      bv = bih[bn] + bhh[bn];
    else if (bg == 1) bv = bih[DD + bn] + bhh[DD + bn];
    else if (bg == 2) bv = bih[2 * DD + bn];
    else              bv = bhh[2 * DD + bn];
    bias[i] = bv;
  }
}

// ---- per-iteration: error GEMV + bf16 cast of state ----
__global__ __launch_bounds__(256) void error_cast(
    const float* S, const float* __restrict__ We, const float* __restrict__ be,
    unsigned short* __restrict__ Sb, float* __restrict__ err) {
  __shared__ float part[4];
  const int row = blockIdx.x;
  const int t = threadIdx.x;
  float4 v = reinterpret_cast<const float4*>(S + (size_t)row * DD)[t];
  float4 w = reinterpret_cast<const float4*>(We)[t];
  float dot = v.x * w.x + v.y * w.y + v.z * w.z + v.w * w.w;
  ushort4 o = make_ushort4(f2bf(v.x), f2bf(v.y), f2bf(v.z), f2bf(v.w));
  reinterpret_cast<ushort4*>(Sb + (size_t)row * DD)[t] = o;
#pragma unroll
  for (int off = 32; off > 0; off >>= 1) dot += __shfl_xor(dot, off);
  if ((t & 63) == 0) part[t >> 6] = dot;
  __syncthreads();
  if (t == 0) err[row] = sigm(part[0] + part[1] + part[2] + part[3] + be[0]);
}

// ---- fused 4-gate GEMM + GRU epilogue ----
// Tile 128M x (4g x 32dg), BK=32, 32 K-tiles. 4 waves (2M x 2N), wave 64x64.
// LDS 32 KB total -> 3 blocks/CU co-resident (independent barriers = wave slip).
// Per tile: vmcnt(4); bar; 8 ds_read; lgkm(0); bar; stage(t+2); 16 MFMA.
// LDS swizzle (64B rows, line-paired): logical (row,k16) at phys slot
// ((((row&1)<<2)|k16) ^ ((row>>1)&7)) within the row's 128B line — same
// involution on the pre-swizzled global source (gload_lds writes linearly).
__global__ __launch_bounds__(256, 3) void gru_fused_gemm(
    const unsigned short* __restrict__ Sb,   // [M][1024] bf16 state
    const unsigned short* __restrict__ Wcat, // [4096][1024] bf16
    const float* __restrict__ bias,          // [4096]
    const float* __restrict__ err,           // [M]
    const float* Sf,                         // [M][1024] f32 h (may alias out)
    float* out, int M) {
  __shared__ alignas(16) unsigned short As[2 * 128 * 32];   // 16 KB (2 slots)
  __shared__ alignas(16) unsigned short Bs[2 * 128 * 32];   // 16 KB (2 slots)

  const int nwg = gridDim.x;               // 8192
  const int bid = blockIdx.x;
  const int swz = (bid & 7) * (nwg >> 3) + (bid >> 3);
  const int db = swz & 31;                 // 0..31
  const int rb = swz >> 5;                 // 0..255

  const int tid = threadIdx.x;
  const int w = tid >> 6;                  // 0..3
  const int lane = tid & 63;
  const int wr = w >> 1, wc = w & 1;

  // ---- staging: 8 A-chunks + 8 B-chunks of 1KB (16 rows x 32k); 2+2 per wave
  const int slog = (lane & 7) ^ (lane >> 3);          // logical slot for this lane's phys pos
  const int rloc = (lane >> 3) * 2 + (slog >> 2);     // row within 16-row chunk
  const int ksrc = (slog & 3) * 8;                    // k-element offset
  const unsigned short* srcA[2];
  const unsigned short* srcB[2];
  unsigned short* dstA[2];
  unsigned short* dstB[2];
#pragma unroll
  for (int i = 0; i < 2; ++i) {
    int c = w + i * 4;                                // chunk 0..7
    int rowA = c * 16 + rloc;                         // 0..127
    srcA[i] = Sb + (size_t)(rb * 128 + rowA) * DD + ksrc;
    int g = rowA >> 5, dgl = rowA & 31;
    srcB[i] = Wcat + (size_t)(g * DD + db * 32 + dgl) * DD + ksrc;
    dstA[i] = As + c * 512;
    dstB[i] = Bs + c * 512;
  }

  // ---- read-side addressing (element offsets)
  const int l15 = lane & 15;
  const int g4 = lane >> 4;                           // k16 slot 0..3
  const int q = l15 >> 1;                             // line-in-16-rows
  const int swzrd = ((((l15 & 1) << 2) | g4) ^ q) * 8;
  const int abase = (wr * 32 + q) * 64 + swzrd;       // + mi*512
  const int bbase = (wc * 8 + q) * 64 + swzrd;        // + g*1024

  f32x4 acc[4][4];
#pragma unroll
  for (int mi = 0; mi < 4; ++mi)
#pragma unroll
    for (int g = 0; g < 4; ++g) acc[mi][g] = f32x4{0.f, 0.f, 0.f, 0.f};

  // prologue: stage tiles 0,1 (8 loads/wave outstanding)
#pragma unroll
  for (int i = 0; i < 2; ++i) {
    gload_lds16(srcA[i], dstA[i]);
    gload_lds16(srcB[i], dstB[i]);
  }
#pragma unroll
  for (int i = 0; i < 2; ++i) {
    gload_lds16(srcA[i] + 32, dstA[i] + 4096);
    gload_lds16(srcB[i] + 32, dstB[i] + 4096);
  }

  for (int t = 0; t < 32; ++t) {
    const int sb = (t & 1) * 4096;
    if (t < 31) asm volatile("s_waitcnt vmcnt(4)" ::: "memory");
    else        asm volatile("s_waitcnt vmcnt(0)" ::: "memory");
    __builtin_amdgcn_s_barrier();

    short8 a[4], b[4];
#pragma unroll
    for (int mi = 0; mi < 4; ++mi)
      a[mi] = *reinterpret_cast<const short8*>(&As[sb + abase + mi * 512]);
#pragma unroll
    for (int g = 0; g < 4; ++g)
      b[g] = *reinterpret_cast<const short8*>(&Bs[sb + bbase + g * 1024]);
    asm volatile("s_waitcnt lgkmcnt(0)" ::: "memory");
    __builtin_amdgcn_s_barrier();               // slot sb now free block-wide

    if (t <= 29) {                              // stage tile t+2 into slot sb
      const int koff = (t + 2) * 32;
#pragma unroll
      for (int i = 0; i < 2; ++i) {
        gload_lds16(srcA[i] + koff, dstA[i] + sb);
        gload_lds16(srcB[i] + koff, dstB[i] + sb);
      }
    }
    __builtin_amdgcn_s_setprio(1);
#pragma unroll
    for (int g = 0; g < 4; ++g)
#pragma unroll
      for (int mi = 0; mi < 4; ++mi)
        acc[mi][g] = __builtin_amdgcn_mfma_f32_16x16x32_bf16(a[mi], b[g], acc[mi][g], 0, 0, 0);
    __builtin_amdgcn_s_setprio(0);
  }

  // ---- epilogue: r,z,n + out = h + e*(1-z)*(n-h)
  const int mbase = rb * 128 + wr * 64;
  const int dg = db * 32 + wc * 16 + l15;
  const float b_r = bias[dg];
  const float b_z = bias[DD + dg];
  const float b_i = bias[2 * DD + dg];
  const float b_h = bias[3 * DD + dg];
#pragma unroll
  for (int mi = 0; mi < 4; ++mi) {
#pragma unroll
    for (int j = 0; j < 4; ++j) {
      int m = mbase + mi * 16 + g4 * 4 + j;
      float e = err[m];
      float h = Sf[(size_t)m * DD + dg];
      float r = sigm(acc[mi][0][j] + b_r);
      float z = sigm(acc[mi][1][j] + b_z);
      float n = tanh_fast(acc[mi][2][j] + b_i + r * (acc[mi][3][j] + b_h));
      out[(size_t)m * DD + dg] = h + e * (1.0f - z) * (n - h);
    }
  }
}

extern "C" void kernel_launch(void* const* d_in, const int* in_sizes, int n_in,
                              void* d_out, int out_size, void* d_ws, size_t ws_size,
                              hipStream_t stream) {
  const float* x   = (const float*)d_in[0];
  const float* Wih = (const float*)d_in[1];
  const float* Whh = (const float*)d_in[2];
  const float* bih = (const float*)d_in[3];
  const float* bhh = (const float*)d_in[4];
  const float* We  = (const float*)d_in[5];
  const float* be  = (const float*)d_in[6];
  float* out = (float*)d_out;
  const int M = in_sizes[0] / DD;   // 32768

  char* ws = (char*)d_ws;
  unsigned short* Sb   = (unsigned short*)ws;
  unsigned short* Wcat = (unsigned short*)(ws + (size_t)M * DD * 2);
  float* bias = (float*)(ws + (size_t)M * DD * 2 + (size_t)4 * DD * DD * 2);
  float* err  = (float*)(ws + (size_t)M * DD * 2 + (size_t)4 * DD * DD * 2 + (size_t)4 * DD * 4);

  prep_weights<<<4096, 256, 0, stream>>>(Wih, Whh, bih, bhh, Wcat, bias);

  const int nwg = (M / 128) * ((4 * DD) / 128);   // 256 * 32 = 8192
  const float* S = x;
  for (int it = 0; it < 2; ++it) {
    error_cast<<<M, 256, 0, stream>>>(S, We, be, Sb, err);
    gru_fused_gemm<<<nwg, 256, 0, stream>>>(Sb, Wcat, bias, err, S, out, M);
    S = out;
  }
}

// Round 7
// 598.596 us; speedup vs baseline: 1.3752x; 1.3752x over previous
//
#include <hip/hip_runtime.h>

#define DD 1024

typedef int   i32x4  __attribute__((ext_vector_type(4)));
typedef int   i32x8  __attribute__((ext_vector_type(8)));
typedef float f32x16 __attribute__((ext_vector_type(16)));

__device__ __forceinline__ float sigm(float x) { return 1.0f / (1.0f + __expf(-x)); }
__device__ __forceinline__ float tanh_fast(float x) {
  float e = __expf(-2.0f * fabsf(x));
  float t = (1.0f - e) / (1.0f + e);
  return copysignf(t, x);
}
__device__ __forceinline__ void gload_lds16(const void* g, void* l) {
  __builtin_amdgcn_global_load_lds((const __attribute__((address_space(1))) void*)g,
                                   (__attribute__((address_space(3))) void*)l, 16, 0, 0);
}
__device__ __forceinline__ unsigned pk_fp8x4(float a, float b, float c, float d) {
  int u = __builtin_amdgcn_cvt_pk_fp8_f32(a, b, 0, false);
  u = __builtin_amdgcn_cvt_pk_fp8_f32(c, d, u, true);
  return (unsigned)u;
}

// ---- one-time weight prep: Wcat8[4][1024][1024] fp8(e4m3, W*32), bias[4][1024] f32
// g=0: Wih_r+Whh_r ; g=1: Wih_z+Whh_z ; g=2: Wih_n ; g=3: Whh_n
__global__ __launch_bounds__(256) void prep_weights(
    const float* __restrict__ Wih, const float* __restrict__ Whh,
    const float* __restrict__ bih, const float* __restrict__ bhh,
    unsigned char* __restrict__ Wcat8, float* __restrict__ bias) {
  int i = blockIdx.x * 256 + threadIdx.x;   // 4-elem units over 4*D*D/4
  int g = i >> 18;
  int rem = i & 262143;
  int n = rem >> 8;
  int k4 = rem & 255;
  const float4* wih4 = reinterpret_cast<const float4*>(Wih);
  const float4* whh4 = reinterpret_cast<const float4*>(Whh);
  float4 v;
  if (g == 0) {
    size_t idx = (size_t)n * 256 + k4;
    float4 a = wih4[idx], b = whh4[idx];
    v = make_float4(a.x + b.x, a.y + b.y, a.z + b.z, a.w + b.w);
  } else if (g == 1) {
    size_t idx = (size_t)(DD + n) * 256 + k4;
    float4 a = wih4[idx], b = whh4[idx];
    v = make_float4(a.x + b.x, a.y + b.y, a.z + b.z, a.w + b.w);
  } else if (g == 2) {
    size_t idx = (size_t)(2 * DD + n) * 256 + k4;
    v = wih4[idx];
  } else {
    size_t idx = (size_t)(2 * DD + n) * 256 + k4;
    v = whh4[idx];
  }
  // scale x32 (exact) so weights leave the e4m3 denormal zone; MX B-scale 2^-5 undoes it
  reinterpret_cast<unsigned*>(Wcat8)[i] =
      pk_fp8x4(v.x * 32.0f, v.y * 32.0f, v.z * 32.0f, v.w * 32.0f);

  if (i < 4 * DD) {
    int bg = i >> 10, bn = i & 1023;
    float bv;
    if (bg == 0)      bv = bih[bn] + bhh[bn];
    else if (bg == 1) bv = bih[DD + bn] + bhh[DD + bn];
    else if (bg == 2) bv = bih[2 * DD + bn];
    else              bv = bhh[2 * DD + bn];
    bias[i] = bv;
  }
}

// ---- per-iteration: error GEMV + fp8 cast of state (single read of state) ----
__global__ __launch_bounds__(256) void error_cast(
    const float* S, const float* __restrict__ We, const float* __restrict__ be,
    unsigned char* __restrict__ Sb8, float* __restrict__ err) {
  __shared__ float part[4];
  const int row = blockIdx.x;
  const int t = threadIdx.x;
  float4 v = reinterpret_cast<const float4*>(S + (size_t)row * DD)[t];
  float4 w = reinterpret_cast<const float4*>(We)[t];
  float dot = v.x * w.x + v.y * w.y + v.z * w.z + v.w * w.w;
  reinterpret_cast<unsigned*>(Sb8 + (size_t)row * DD)[t] = pk_fp8x4(v.x, v.y, v.z, v.w);
#pragma unroll
  for (int off = 32; off > 0; off >>= 1) dot += __shfl_xor(dot, off);
  if ((t & 63) == 0) part[t >> 6] = dot;
  __syncthreads();
  if (t == 0) err[row] = sigm(part[0] + part[1] + part[2] + part[3] + be[0]);
}

// ---- fused 4-gate MX-fp8 GEMM + GRU epilogue ----
// Tile 128M x 128N(4g x 32dg), BK=64B, 16 K-tiles, 4 waves; wave = 32M x 128N
// via 4x mfma_scale_f32_32x32x64_f8f6f4 (A scale 1.0=127, B scale 2^-5=122).
// LDS 32 KB (2 slots) -> 3 blocks/CU. Granule-subtiled layout, XOR g^((row>>3)&3):
// conflict-free ds_read_b128 AND linear gload_lds dst (inverse perm on global src).
__global__ __launch_bounds__(256, 3) void gru_fused_gemm(
    const unsigned char* __restrict__ Sb8,   // [M][1024] fp8 state
    const unsigned char* __restrict__ Wcat8, // [4096][1024] fp8 (W*32)
    const float* __restrict__ bias,          // [4096]
    const float* __restrict__ err,           // [M]
    const float* Sf,                         // [M][1024] f32 h (may alias out)
    float* out, int M) {
  __shared__ alignas(16) unsigned char As[2 * 8192];   // 16 KB
  __shared__ alignas(16) unsigned char Bs[2 * 8192];   // 16 KB

  const int nwg = gridDim.x;               // 8192
  const int bid = blockIdx.x;
  const int swz = (bid & 7) * (nwg >> 3) + (bid >> 3);
  const int db = swz & 31;                 // dg block 0..31
  const int rb = swz >> 5;                 // row block 0..255

  const int tid = threadIdx.x;
  const int w = tid >> 6;                  // 0..3
  const int lane = tid & 63;
  const int l31 = lane & 31;
  const int h = lane >> 5;

  // ---- staging: 16 x 1KB instrs (8 A + 8 B); wave w: A{w,w+4}, B{w,w+4}
  // instr j covers rows 16j..16j+15; lane: row = 16j + 8h + (lane&7),
  // source granule = (l31>>3) ^ ((2j+h)&3)  [inverse of read-side XOR]
  const unsigned char* srcA[2];
  const unsigned char* srcB[2];
  unsigned char* dstA[2];
  unsigned char* dstB[2];
#pragma unroll
  for (int i = 0; i < 2; ++i) {
    int j = w + i * 4;
    int row = 16 * j + 8 * h + (lane & 7);
    int gr = (l31 >> 3) ^ ((2 * j + h) & 3);
    srcA[i] = Sb8 + (size_t)(rb * 128 + row) * DD + gr * 16;
    int gate = row >> 5, dgl = row & 31;
    srcB[i] = Wcat8 + (size_t)(gate * DD + db * 32 + dgl) * DD + gr * 16;
    dstA[i] = As + j * 1024;
    dstB[i] = Bs + j * 1024;
  }

  // ---- frag read offsets: logical (row,g16) at (row>>3)*512 + (g^((row>>3)&3))*128 + (row&7)*16
  const int kb = lane >> 5;                // K-block 0/1 (32 elems each)
  const int arow = w * 32 + l31;
  const int am = (arow >> 3) & 3;
  const int abase = (arow >> 3) * 512 + (arow & 7) * 16;
  const int aoff0 = abase + (((2 * kb) ^ am) * 128);
  const int aoff1 = abase + (((2 * kb + 1) ^ am) * 128);
  int boff0[4], boff1[4];
#pragma unroll
  for (int g = 0; g < 4; ++g) {
    int brow = g * 32 + l31;
    int bm = (brow >> 3) & 3;
    int bb = (brow >> 3) * 512 + (brow & 7) * 16;
    boff0[g] = bb + (((2 * kb) ^ bm) * 128);
    boff1[g] = bb + (((2 * kb + 1) ^ bm) * 128);
  }

  f32x16 acc[4];
#pragma unroll
  for (int g = 0; g < 4; ++g)
#pragma unroll
    for (int r = 0; r < 16; ++r) acc[g][r] = 0.0f;

  // prologue: stage tiles 0,1 (8 loads/wave outstanding)
#pragma unroll
  for (int i = 0; i < 2; ++i) {
    gload_lds16(srcA[i], dstA[i]);
    gload_lds16(srcB[i], dstB[i]);
  }
#pragma unroll
  for (int i = 0; i < 2; ++i) {
    gload_lds16(srcA[i] + 64, dstA[i] + 8192);
    gload_lds16(srcB[i] + 64, dstB[i] + 8192);
  }

  for (int t = 0; t < 16; ++t) {
    const int sb = (t & 1) * 8192;
    if (t < 15) asm volatile("s_waitcnt vmcnt(4)" ::: "memory");
    else        asm volatile("s_waitcnt vmcnt(0)" ::: "memory");
    __builtin_amdgcn_s_barrier();

    const unsigned char* Ab = As + sb;
    const unsigned char* Bb = Bs + sb;
    i32x4 a0 = *reinterpret_cast<const i32x4*>(Ab + aoff0);
    i32x4 a1 = *reinterpret_cast<const i32x4*>(Ab + aoff1);
    i32x8 a = __builtin_shufflevector(a0, a1, 0, 1, 2, 3, 4, 5, 6, 7);
    i32x8 bf[4];
#pragma unroll
    for (int g = 0; g < 4; ++g) {
      i32x4 b0 = *reinterpret_cast<const i32x4*>(Bb + boff0[g]);
      i32x4 b1 = *reinterpret_cast<const i32x4*>(Bb + boff1[g]);
      bf[g] = __builtin_shufflevector(b0, b1, 0, 1, 2, 3, 4, 5, 6, 7);
    }
    asm volatile("s_waitcnt lgkmcnt(0)" ::: "memory");
    __builtin_amdgcn_s_barrier();               // slot sb free block-wide

    if (t <= 13) {                              // stage tile t+2 into slot sb
      const int koff = (t + 2) * 64;
#pragma unroll
      for (int i = 0; i < 2; ++i) {
        gload_lds16(srcA[i] + koff, dstA[i] + sb);
        gload_lds16(srcB[i] + koff, dstB[i] + sb);
      }
    }
    __builtin_amdgcn_s_setprio(1);
#pragma unroll
    for (int g = 0; g < 4; ++g)
      acc[g] = __builtin_amdgcn_mfma_scale_f32_32x32x64_f8f6f4(
          a, bf[g], acc[g], 0, 0, 0, 127, 0, 122);
    __builtin_amdgcn_s_setprio(0);
  }

  // ---- epilogue: r,z,n + out = h + e*(1-z)*(n-h)
  // C/D 32x32 layout: col = lane&31, row = (reg&3) + 8*(reg>>2) + 4*(lane>>5)
  const int dgcol = db * 32 + l31;
  const float b_r = bias[dgcol];
  const float b_z = bias[DD + dgcol];
  const float b_i = bias[2 * DD + dgcol];
  const float b_h = bias[3 * DD + dgcol];
#pragma unroll
  for (int reg = 0; reg < 16; ++reg) {
    int rowf = (reg & 3) + 8 * (reg >> 2) + 4 * h;
    int m = rb * 128 + w * 32 + rowf;
    float e = err[m];
    float hh = Sf[(size_t)m * DD + dgcol];
    float r = sigm(acc[0][reg] + b_r);
    float z = sigm(acc[1][reg] + b_z);
    float n = tanh_fast(acc[2][reg] + b_i + r * (acc[3][reg] + b_h));
    out[(size_t)m * DD + dgcol] = hh + e * (1.0f - z) * (n - hh);
  }
}

extern "C" void kernel_launch(void* const* d_in, const int* in_sizes, int n_in,
                              void* d_out, int out_size, void* d_ws, size_t ws_size,
                              hipStream_t stream) {
  const float* x   = (const float*)d_in[0];
  const float* Wih = (const float*)d_in[1];
  const float* Whh = (const float*)d_in[2];
  const float* bih = (const float*)d_in[3];
  const float* bhh = (const float*)d_in[4];
  const float* We  = (const float*)d_in[5];
  const float* be  = (const float*)d_in[6];
  float* out = (float*)d_out;
  const int M = in_sizes[0] / DD;   // 32768

  char* ws = (char*)d_ws;
  unsigned char* Sb8   = (unsigned char*)ws;                         // M*D = 32 MB
  unsigned char* Wcat8 = (unsigned char*)(ws + (size_t)M * DD);      // 4 MB
  float* bias = (float*)(ws + (size_t)M * DD + (size_t)4 * DD * DD);
  float* err  = (float*)(ws + (size_t)M * DD + (size_t)4 * DD * DD + (size_t)4 * DD * 4);

  prep_weights<<<4096, 256, 0, stream>>>(Wih, Whh, bih, bhh, Wcat8, bias);

  const int nwg = (M / 128) * 32;   // 8192
  const float* S = x;
  for (int it = 0; it < 2; ++it) {
    error_cast<<<M, 256, 0, stream>>>(S, We, be, Sb8, err);
    gru_fused_gemm<<<nwg, 256, 0, stream>>>(Sb8, Wcat8, bias, err, S, out, M);
    S = out;
  }
}

// Round 8
// 515.950 us; speedup vs baseline: 1.5955x; 1.1602x over previous
//
#include <hip/hip_runtime.h>

#define DD 1024

typedef int   i32x4  __attribute__((ext_vector_type(4)));
typedef int   i32x8  __attribute__((ext_vector_type(8)));
typedef float f32x4  __attribute__((ext_vector_type(4)));

__device__ __forceinline__ float sigm(float x) { return 1.0f / (1.0f + __expf(-x)); }
__device__ __forceinline__ float tanh_fast(float x) {
  float e = __expf(-2.0f * fabsf(x));
  float t = (1.0f - e) / (1.0f + e);
  return copysignf(t, x);
}
__device__ __forceinline__ void gload_lds16(const void* g, void* l) {
  __builtin_amdgcn_global_load_lds((const __attribute__((address_space(1))) void*)g,
                                   (__attribute__((address_space(3))) void*)l, 16, 0, 0);
}
__device__ __forceinline__ unsigned pk_fp8x4(float a, float b, float c, float d) {
  int u = __builtin_amdgcn_cvt_pk_fp8_f32(a, b, 0, false);
  u = __builtin_amdgcn_cvt_pk_fp8_f32(c, d, u, true);
  return (unsigned)u;
}

// ---- one-time weight prep: Wcat8[4][1024][1024] fp8(e4m3, W*32), bias[4][1024] f32
// g=0: Wih_r+Whh_r ; g=1: Wih_z+Whh_z ; g=2: Wih_n ; g=3: Whh_n
__global__ __launch_bounds__(256) void prep_weights(
    const float* __restrict__ Wih, const float* __restrict__ Whh,
    const float* __restrict__ bih, const float* __restrict__ bhh,
    unsigned char* __restrict__ Wcat8, float* __restrict__ bias) {
  int i = blockIdx.x * 256 + threadIdx.x;   // 4-elem units over 4*D*D/4
  int g = i >> 18;
  int rem = i & 262143;
  int n = rem >> 8;
  int k4 = rem & 255;
  const float4* wih4 = reinterpret_cast<const float4*>(Wih);
  const float4* whh4 = reinterpret_cast<const float4*>(Whh);
  float4 v;
  if (g == 0) {
    size_t idx = (size_t)n * 256 + k4;
    float4 a = wih4[idx], b = whh4[idx];
    v = make_float4(a.x + b.x, a.y + b.y, a.z + b.z, a.w + b.w);
  } else if (g == 1) {
    size_t idx = (size_t)(DD + n) * 256 + k4;
    float4 a = wih4[idx], b = whh4[idx];
    v = make_float4(a.x + b.x, a.y + b.y, a.z + b.z, a.w + b.w);
  } else if (g == 2) {
    size_t idx = (size_t)(2 * DD + n) * 256 + k4;
    v = wih4[idx];
  } else {
    size_t idx = (size_t)(2 * DD + n) * 256 + k4;
    v = whh4[idx];
  }
  // scale x32 (exact) so weights leave the e4m3 denormal zone; MX B-scale 2^-5 undoes it
  reinterpret_cast<unsigned*>(Wcat8)[i] =
      pk_fp8x4(v.x * 32.0f, v.y * 32.0f, v.z * 32.0f, v.w * 32.0f);

  if (i < 4 * DD) {
    int bg = i >> 10, bn = i & 1023;
    float bv;
    if (bg == 0)      bv = bih[bn] + bhh[bn];
    else if (bg == 1) bv = bih[DD + bn] + bhh[DD + bn];
    else if (bg == 2) bv = bih[2 * DD + bn];
    else              bv = bhh[2 * DD + bn];
    bias[i] = bv;
  }
}

// ---- per-iteration: error GEMV + fp8 cast of state (single read of state) ----
__global__ __launch_bounds__(256) void error_cast(
    const float* S, const float* __restrict__ We, const float* __restrict__ be,
    unsigned char* __restrict__ Sb8, float* __restrict__ err) {
  __shared__ float part[4];
  const int row = blockIdx.x;
  const int t = threadIdx.x;
  float4 v = reinterpret_cast<const float4*>(S + (size_t)row * DD)[t];
  float4 w = reinterpret_cast<const float4*>(We)[t];
  float dot = v.x * w.x + v.y * w.y + v.z * w.z + v.w * w.w;
  reinterpret_cast<unsigned*>(Sb8 + (size_t)row * DD)[t] = pk_fp8x4(v.x, v.y, v.z, v.w);
#pragma unroll
  for (int off = 32; off > 0; off >>= 1) dot += __shfl_xor(dot, off);
  if ((t & 63) == 0) part[t >> 6] = dot;
  __syncthreads();
  if (t == 0) err[row] = sigm(part[0] + part[1] + part[2] + part[3] + be[0]);
}

// ---- fused 4-gate MX-fp8 GEMM + GRU epilogue ----
// Tile 128M x 128N(4g x 32dg), BK=128, 8 K-tiles, 4 waves (2M x 2N), wave 64x64.
// MFMA: mfma_scale_f32_16x16x128_f8f6f4 -> 16 MFMA : 16 ds_read_b128 per wave
// per K-tile (1.0 read/MFMA vs R7's 2.5). 2 barriers per 16-MFMA cluster.
// LDS 64 KB (2 slots) -> 2 blocks/CU. Swizzle: 128B rows, 16B granules,
// phys_g = g ^ (row&7); linear gload_lds dst + inverse-perm per-lane global src.
// N-dim order: n_t = wc*64 + gate*16 + dgl15 so each wave owns all 4 gates.
__global__ __launch_bounds__(256, 2) void gru_fused_gemm(
    const unsigned char* __restrict__ Sb8,   // [M][1024] fp8 state
    const unsigned char* __restrict__ Wcat8, // [4096][1024] fp8 (W*32)
    const float* __restrict__ bias,          // [4096]
    const float* __restrict__ err,           // [M]
    const float* Sf,                         // [M][1024] f32 h (may alias out)
    float* out, int M) {
  __shared__ alignas(16) unsigned char As[2 * 16384];   // 32 KB
  __shared__ alignas(16) unsigned char Bs[2 * 16384];   // 32 KB

  const int nwg = gridDim.x;               // 8192
  const int bid = blockIdx.x;
  const int swz = (bid & 7) * (nwg >> 3) + (bid >> 3);
  const int db = swz & 31;                 // dg block 0..31
  const int rb = swz >> 5;                 // row block 0..255

  const int tid = threadIdx.x;
  const int w = tid >> 6;                  // 0..3
  const int lane = tid & 63;
  const int l15 = lane & 15;
  const int q = lane >> 4;                 // 0..3
  const int wr = w >> 1, wc = w & 1;

  // ---- staging: 32 x 1KB instrs (16 A + 16 B); wave w: instrs w+4i.
  // instr j covers tile rows 8j..8j+7; lane l -> row = 8j + (l>>3),
  // phys granule = l&7, logical granule = (l&7) ^ (l>>3)  [row&7 == l>>3]
  const int l8r = lane >> 3;
  const int glog = (lane & 7) ^ l8r;
  const unsigned char* srcA[4];
  const unsigned char* srcB[4];
  unsigned char* dstA[4];
  unsigned char* dstB[4];
#pragma unroll
  for (int i = 0; i < 4; ++i) {
    int j = w + i * 4;
    int row = j * 8 + l8r;                 // 0..127
    srcA[i] = Sb8 + (size_t)(rb * 128 + row) * DD + glog * 16;
    // n_t -> (wc_part, gate, dgl): bits [6]=wc, [5:4]=gate, [3:0]=dgl low
    int gate = (row >> 4) & 3;
    int dgl = (row & 15) + (row >> 6) * 16;
    srcB[i] = Wcat8 + (size_t)(gate * DD + db * 32 + dgl) * DD + glog * 16;
    dstA[i] = As + j * 1024;
    dstB[i] = Bs + j * 1024;
  }

  // ---- frag read offsets: row*128 + ((2q+s) ^ (lane&7))*16
  const int lx = lane & 7;
  const int s0 = ((2 * q) ^ lx) * 16;
  const int s1 = ((2 * q + 1) ^ lx) * 16;
  int abase[4], bbase[4];
#pragma unroll
  for (int mi = 0; mi < 4; ++mi) abase[mi] = (wr * 64 + mi * 16 + l15) * 128;
#pragma unroll
  for (int g = 0; g < 4; ++g)   bbase[g] = (wc * 64 + g * 16 + l15) * 128;

  f32x4 acc[4][4];
#pragma unroll
  for (int mi = 0; mi < 4; ++mi)
#pragma unroll
    for (int g = 0; g < 4; ++g) acc[mi][g] = f32x4{0.f, 0.f, 0.f, 0.f};

  auto stage = [&](int t) {
    const int slot = (t & 1) * 16384;
    const int koff = t * 128;
#pragma unroll
    for (int i = 0; i < 4; ++i) {
      gload_lds16(srcA[i] + koff, dstA[i] + slot);
      gload_lds16(srcB[i] + koff, dstB[i] + slot);
    }
  };

  stage(0);
  stage(1);

  for (int t = 0; t < 8; ++t) {
    const int sb = (t & 1) * 16384;
    if (t < 7) asm volatile("s_waitcnt vmcnt(8)" ::: "memory");
    else       asm volatile("s_waitcnt vmcnt(0)" ::: "memory");
    __builtin_amdgcn_s_barrier();

    const unsigned char* Ab = As + sb;
    const unsigned char* Bb = Bs + sb;
    i32x8 a[4], b[4];
#pragma unroll
    for (int mi = 0; mi < 4; ++mi) {
      i32x4 a0 = *reinterpret_cast<const i32x4*>(Ab + abase[mi] + s0);
      i32x4 a1 = *reinterpret_cast<const i32x4*>(Ab + abase[mi] + s1);
      a[mi] = __builtin_shufflevector(a0, a1, 0, 1, 2, 3, 4, 5, 6, 7);
    }
#pragma unroll
    for (int g = 0; g < 4; ++g) {
      i32x4 b0 = *reinterpret_cast<const i32x4*>(Bb + bbase[g] + s0);
      i32x4 b1 = *reinterpret_cast<const i32x4*>(Bb + bbase[g] + s1);
      b[g] = __builtin_shufflevector(b0, b1, 0, 1, 2, 3, 4, 5, 6, 7);
    }
    asm volatile("s_waitcnt lgkmcnt(0)" ::: "memory");
    __builtin_amdgcn_s_barrier();               // slot sb free block-wide

    if (t <= 5) stage(t + 2);                   // into freed slot sb

    __builtin_amdgcn_s_setprio(1);
#pragma unroll
    for (int g = 0; g < 4; ++g)
#pragma unroll
      for (int mi = 0; mi < 4; ++mi)
        acc[mi][g] = __builtin_amdgcn_mfma_scale_f32_16x16x128_f8f6f4(
            a[mi], b[g], acc[mi][g], 0, 0, 0, 0x7F7F7F7F, 0, 0x7A7A7A7A);
    __builtin_amdgcn_s_setprio(0);
  }

  // ---- epilogue: r,z,n + out = h + e*(1-z)*(n-h)
  // C/D 16x16 layout: col = lane&15 (N), row = q*4 + reg (M)
  const int dgcol = db * 32 + wc * 16 + l15;
  const float b_r = bias[dgcol];
  const float b_z = bias[DD + dgcol];
  const float b_i = bias[2 * DD + dgcol];
  const float b_h = bias[3 * DD + dgcol];
#pragma unroll
  for (int mi = 0; mi < 4; ++mi) {
#pragma unroll
    for (int j = 0; j < 4; ++j) {
      int m = rb * 128 + wr * 64 + mi * 16 + q * 4 + j;
      float e = err[m];
      float hh = Sf[(size_t)m * DD + dgcol];
      float r = sigm(acc[mi][0][j] + b_r);
      float z = sigm(acc[mi][1][j] + b_z);
      float n = tanh_fast(acc[mi][2][j] + b_i + r * (acc[mi][3][j] + b_h));
      out[(size_t)m * DD + dgcol] = hh + e * (1.0f - z) * (n - hh);
    }
  }
}

extern "C" void kernel_launch(void* const* d_in, const int* in_sizes, int n_in,
                              void* d_out, int out_size, void* d_ws, size_t ws_size,
                              hipStream_t stream) {
  const float* x   = (const float*)d_in[0];
  const float* Wih = (const float*)d_in[1];
  const float* Whh = (const float*)d_in[2];
  const float* bih = (const float*)d_in[3];
  const float* bhh = (const float*)d_in[4];
  const float* We  = (const float*)d_in[5];
  const float* be  = (const float*)d_in[6];
  float* out = (float*)d_out;
  const int M = in_sizes[0] / DD;   // 32768

  char* ws = (char*)d_ws;
  unsigned char* Sb8   = (unsigned char*)ws;                         // M*D = 32 MB
  unsigned char* Wcat8 = (unsigned char*)(ws + (size_t)M * DD);      // 4 MB
  float* bias = (float*)(ws + (size_t)M * DD + (size_t)4 * DD * DD);
  float* err  = (float*)(ws + (size_t)M * DD + (size_t)4 * DD * DD + (size_t)4 * DD * 4);

  prep_weights<<<4096, 256, 0, stream>>>(Wih, Whh, bih, bhh, Wcat8, bias);

  const int nwg = (M / 128) * 32;   // 8192
  const float* S = x;
  for (int it = 0; it < 2; ++it) {
    error_cast<<<M, 256, 0, stream>>>(S, We, be, Sb8, err);
    gru_fused_gemm<<<nwg, 256, 0, stream>>>(Sb8, Wcat8, bias, err, S, out, M);
    S = out;
  }
}